// Round 1
// baseline (919.059 us; speedup 1.0000x reference)
//
#include <hip/hip_runtime.h>
#include <math.h>

#define D_DIM 4096
#define E_DIM 64
#define NTOK  16384
#define MT    32     // tokens per block
#define KC    64     // K chunk
#define XSTR  68     // x tile LDS stride (floats)
#define WSTR  132    // w tile LDS stride (floats)
#define XS_OFF 0
#define WS_OFF (MT * XSTR)              /* 2176 */
#define NB_OFF (WS_OFF + MT * WSTR)     /* 6400 */
#define SMEM_FLOATS (WS_OFF + KC * WSTR) /* 10624 floats = 42.5 KB */

__global__ __launch_bounds__(128)
void router_kernel(const float* __restrict__ x,
                   const float* __restrict__ noise,
                   const float* __restrict__ Wr,
                   const float* __restrict__ br,
                   const float* __restrict__ Wn,
                   const float* __restrict__ bn,
                   float* __restrict__ out)
{
    __shared__ float smem[SMEM_FLOATS];
    const int tid = threadIdx.x;
    const int tx = tid & 15;       // col-group 0..15
    const int ty = tid >> 4;       // token-group 0..7
    const int tb = ty << 2;        // token base within tile (4 tokens)
    const int eb = tx << 3;        // col base (8 cols)
    const int t0 = blockIdx.x * MT;

    // staging roles
    const int stok  = tid >> 2;          // 0..31 (token)
    const int skoff = (tid & 3) << 4;    // 0/16/32/48
    const int wrow  = tid >> 5;          // 0..3
    const int whalf = (tid >> 4) & 1;    // 0 = route, 1 = noise
    const int wf4   = (tid & 15) << 2;   // 0..60
    const float* wbase = whalf ? Wn : Wr;
    const float* xrow  = x + (size_t)(t0 + stok) * D_DIM + skoff;

    float acc[4][8];
#pragma unroll
    for (int i = 0; i < 4; ++i)
#pragma unroll
        for (int j = 0; j < 8; ++j) acc[i][j] = 0.0f;

    // ---- preload chunk 0 into registers ----
    float4 xr[4];
    float4 wr[16];
#pragma unroll
    for (int u = 0; u < 4; ++u) xr[u] = ((const float4*)xrow)[u];
#pragma unroll
    for (int r = 0; r < 16; ++r) {
        int k = (r << 2) + wrow;
        wr[r] = *(const float4*)(wbase + (size_t)k * E_DIM + wf4);
    }

    // ---- K loop: regs -> LDS, prefetch next chunk, compute ----
    for (int k0 = 0;;) {
        {
            float* d = smem + XS_OFF + stok * XSTR + skoff;
#pragma unroll
            for (int u = 0; u < 4; ++u) ((float4*)d)[u] = xr[u];
        }
#pragma unroll
        for (int r = 0; r < 16; ++r) {
            int k = (r << 2) + wrow;
            *(float4*)(smem + WS_OFF + k * WSTR + (whalf << 6) + wf4) = wr[r];
        }
        __syncthreads();

        const int kn = k0 + KC;
        if (kn < D_DIM) {
            const float* xp = xrow + kn;
#pragma unroll
            for (int u = 0; u < 4; ++u) xr[u] = ((const float4*)xp)[u];
#pragma unroll
            for (int r = 0; r < 16; ++r) {
                int k = (r << 2) + wrow;
                wr[r] = *(const float4*)(wbase + (size_t)(kn + k) * E_DIM + wf4);
            }
        }

#pragma unroll 2
        for (int k = 0; k < KC; k += 4) {
            float xv[4][4];
#pragma unroll
            for (int i = 0; i < 4; ++i)
                *(float4*)xv[i] = *(const float4*)(smem + XS_OFF + (tb + i) * XSTR + k);
#pragma unroll
            for (int kk = 0; kk < 4; ++kk) {
                float wv[8];
                const float* wp = smem + WS_OFF + (k + kk) * WSTR + eb;
                *(float4*)&wv[0] = *(const float4*)wp;
                *(float4*)&wv[4] = *(const float4*)(wp + 4);
#pragma unroll
                for (int i = 0; i < 4; ++i)
#pragma unroll
                    for (int j = 0; j < 8; ++j)
                        acc[i][j] = fmaf(xv[i][kk], wv[j], acc[i][j]);
            }
        }
        k0 = kn;
        if (k0 >= D_DIM) break;
        __syncthreads();
    }

    __syncthreads();  // protect ws region before reuse as logits buffer

    // ---- accumulators -> LDS logits [MT][WSTR] ----
    float* lg = smem + WS_OFF;
#pragma unroll
    for (int i = 0; i < 4; ++i) {
        *(float4*)(lg + (tb + i) * WSTR + eb)     = *(float4*)&acc[i][0];
        *(float4*)(lg + (tb + i) * WSTR + eb + 4) = *(float4*)&acc[i][4];
    }
    // stage noise tile (coalesced)
    {
        const float* g = noise + (size_t)(t0 + stok) * E_DIM + skoff;
        float* d = smem + NB_OFF + stok * XSTR + skoff;
#pragma unroll
        for (int u = 0; u < 4; ++u) ((float4*)d)[u] = ((const float4*)g)[u];
    }
    __syncthreads();

    // ---- per-token epilogue: bias + noisy softplus + softmax + top-8 ----
    if (tid < MT) {
        float* row = lg + tid * WSTR;                 // [0..63]=route, [64..127]=noise logits
        const float* nb = smem + NB_OFF + tid * XSTR;
        float* pb = smem + XS_OFF + tid * XSTR;       // probs buffer
        float m = -1e30f;
        for (int e = 0; e < E_DIM; ++e) {
            float rl = row[e] + br[e];
            float nl = row[E_DIM + e] + bn[e];
            float sp = log1pf(expf(-fabsf(nl))) + fmaxf(nl, 0.0f);  // stable softplus
            float v = rl + nb[e] * sp;
            row[e] = v;
            m = fmaxf(m, v);
        }
        float s = 0.0f;
        for (int e = 0; e < E_DIM; ++e) {
            float p = expf(row[e] - m);
            pb[e] = p;
            s += p;
        }
        for (int e = 0; e < E_DIM; ++e) pb[e] = pb[e] / s;

        unsigned long long sel = 0ull;
        float wv[8]; int wi[8]; float tsum = 0.0f;
        for (int j = 0; j < 8; ++j) {
            float best = -1.0f; int bi = 0;
            for (int e = 0; e < E_DIM; ++e) {
                float p = pb[e];
                if (!((sel >> e) & 1ull) && p > best) { best = p; bi = e; }  // strict > : lowest index wins ties
            }
            sel |= (1ull << bi);
            wv[j] = best; wi[j] = bi; tsum += best;
        }
        const size_t T = (size_t)t0 + tid;
        float* ow = out + T * 8;                       // output 0: weighted
        float* oi = out + (size_t)NTOK * 8 + T * 8;    // output 1: indices (as float)
#pragma unroll
        for (int j = 0; j < 8; ++j) {
            ow[j] = wv[j] / tsum;
            oi[j] = (float)wi[j];
        }
    }
    __syncthreads();

    // ---- cooperative coalesced probs store (output 2) ----
    {
        const float* s4 = smem + XS_OFF + stok * XSTR + skoff;
        float* d4 = out + (size_t)NTOK * 16 + (size_t)(t0 + stok) * E_DIM + skoff;
#pragma unroll
        for (int u = 0; u < 4; ++u) ((float4*)d4)[u] = ((const float4*)s4)[u];
    }
}

extern "C" void kernel_launch(void* const* d_in, const int* in_sizes, int n_in,
                              void* d_out, int out_size, void* d_ws, size_t ws_size,
                              hipStream_t stream) {
    const float* x     = (const float*)d_in[0];
    const float* noise = (const float*)d_in[1];
    const float* Wr    = (const float*)d_in[2];
    const float* br    = (const float*)d_in[3];
    const float* Wn    = (const float*)d_in[4];
    const float* bn    = (const float*)d_in[5];
    float* out = (float*)d_out;
    dim3 grid(NTOK / MT), block(128);
    hipLaunchKernelGGL(router_kernel, grid, block, 0, stream,
                       x, noise, Wr, br, Wn, bn, out);
}